// Round 4
// baseline (1669.455 us; speedup 1.0000x reference)
//
#include <hip/hip_runtime.h>
#include <hip/hip_bf16.h>
#include <math.h>

typedef __bf16 bf16_t;
typedef bf16_t bf16x8 __attribute__((ext_vector_type(8)));
typedef bf16_t bf16x2 __attribute__((ext_vector_type(2)));
typedef float  f32x4  __attribute__((ext_vector_type(4)));
typedef float  f32x2  __attribute__((ext_vector_type(2)));

__device__ __forceinline__ int clampi(int v, int n) {
    return v < 0 ? 0 : (v > n - 1 ? n - 1 : v);
}

// ---------------------------------------------------------------------------
// bf16 MFMA GEMM: C[M,NC] = A[M,128] @ BT[NC,128]^T (+fp32 bias, relu)
// In-place Cb==A is safe: each wave reads only its own 16-row strip before
// writing it.
// ---------------------------------------------------------------------------
template<int NC>
__global__ __launch_bounds__(256) void gemm128(const bf16_t* __restrict__ A,
        const bf16_t* __restrict__ BT, const float* __restrict__ bias,
        float* __restrict__ Cf, bf16_t* __restrict__ Cb, int M, int dorelu)
{
    constexpr int NT = NC / 16;
    int wave = threadIdx.x >> 6, lane = threadIdx.x & 63;
    int mbase = (blockIdx.x * 4 + wave) * 16;
    if (mbase >= M) return;
    int r = lane & 15, q = lane >> 4;
    int arow = mbase + r; if (arow > M - 1) arow = M - 1;
    f32x4 acc[NT];
#pragma unroll
    for (int t = 0; t < NT; ++t) acc[t] = f32x4{0.f, 0.f, 0.f, 0.f};
    const bf16_t* aptr = A + (size_t)arow * 128 + q * 8;
#pragma unroll
    for (int kk = 0; kk < 4; ++kk) {
        bf16x8 af = *(const bf16x8*)(aptr + kk * 32);
#pragma unroll
        for (int t = 0; t < NT; ++t) {
            bf16x8 bfg = *(const bf16x8*)(BT + (size_t)(t * 16 + r) * 128 + kk * 32 + q * 8);
            acc[t] = __builtin_amdgcn_mfma_f32_16x16x32_bf16(af, bfg, acc[t], 0, 0, 0);
        }
    }
#pragma unroll
    for (int t = 0; t < NT; ++t) {
#pragma unroll
        for (int i = 0; i < 4; ++i) {
            int row = mbase + q * 4 + i;
            if (row < M) {
                int col = t * 16 + r;
                float v = acc[t][i];
                if (bias) v += bias[col];
                if (dorelu) v = fmaxf(v, 0.f);
                if (Cf) Cf[(size_t)row * NC + col] = v;
                if (Cb) Cb[(size_t)row * NC + col] = (bf16_t)v;
            }
        }
    }
}

// ---------------------------------------------------------------------------
// Fused GRU: per 16-row strip compute gi = xb@wiT+bi, gh = prev@whT+bh and
// the gate, writing h_new directly.
// ---------------------------------------------------------------------------
__global__ __launch_bounds__(256) void gru_k(const bf16_t* __restrict__ xb,
        const float* __restrict__ prevf, const bf16_t* __restrict__ wiT,
        const bf16_t* __restrict__ whT, const float* __restrict__ bi,
        const float* __restrict__ bh, float* __restrict__ hnew, int M)
{
    int wave = threadIdx.x >> 6, lane = threadIdx.x & 63;
    int mbase = (blockIdx.x * 4 + wave) * 16;
    if (mbase >= M) return;
    int r = lane & 15, q = lane >> 4;
    int arow = mbase + r; if (arow > M - 1) arow = M - 1;
    bf16x8 ax[4], ap[4];
#pragma unroll
    for (int kk = 0; kk < 4; ++kk) {
        ax[kk] = *(const bf16x8*)(xb + (size_t)arow * 128 + kk * 32 + q * 8);
        f32x4 p0 = *(const f32x4*)(prevf + (size_t)arow * 128 + kk * 32 + q * 8);
        f32x4 p1 = *(const f32x4*)(prevf + (size_t)arow * 128 + kk * 32 + q * 8 + 4);
        bf16x8 t;
#pragma unroll
        for (int j = 0; j < 4; ++j) { t[j] = (bf16_t)p0[j]; t[j + 4] = (bf16_t)p1[j]; }
        ap[kk] = t;
    }
#pragma unroll
    for (int t3 = 0; t3 < 8; ++t3) {
        f32x4 gi0{0.f,0.f,0.f,0.f}, gi1{0.f,0.f,0.f,0.f}, gi2{0.f,0.f,0.f,0.f};
        f32x4 gh0{0.f,0.f,0.f,0.f}, gh1{0.f,0.f,0.f,0.f}, gh2{0.f,0.f,0.f,0.f};
#pragma unroll
        for (int kk = 0; kk < 4; ++kk) {
            const bf16_t* wi = wiT + (size_t)(t3 * 16 + r) * 128 + kk * 32 + q * 8;
            const bf16_t* wh = whT + (size_t)(t3 * 16 + r) * 128 + kk * 32 + q * 8;
            gi0 = __builtin_amdgcn_mfma_f32_16x16x32_bf16(ax[kk], *(const bf16x8*)wi, gi0, 0, 0, 0);
            gi1 = __builtin_amdgcn_mfma_f32_16x16x32_bf16(ax[kk], *(const bf16x8*)(wi + 128 * 128), gi1, 0, 0, 0);
            gi2 = __builtin_amdgcn_mfma_f32_16x16x32_bf16(ax[kk], *(const bf16x8*)(wi + 256 * 128), gi2, 0, 0, 0);
            gh0 = __builtin_amdgcn_mfma_f32_16x16x32_bf16(ap[kk], *(const bf16x8*)wh, gh0, 0, 0, 0);
            gh1 = __builtin_amdgcn_mfma_f32_16x16x32_bf16(ap[kk], *(const bf16x8*)(wh + 128 * 128), gh1, 0, 0, 0);
            gh2 = __builtin_amdgcn_mfma_f32_16x16x32_bf16(ap[kk], *(const bf16x8*)(wh + 256 * 128), gh2, 0, 0, 0);
        }
        int f = t3 * 16 + r;
        float bif0 = bi[f], bif1 = bi[128 + f], bif2 = bi[256 + f];
        float bhf0 = bh[f], bhf1 = bh[128 + f], bhf2 = bh[256 + f];
#pragma unroll
        for (int i = 0; i < 4; ++i) {
            int row = mbase + q * 4 + i;
            if (row < M) {
                float ir = gi0[i] + bif0, hr = gh0[i] + bhf0;
                float iz = gi1[i] + bif1, hz = gh1[i] + bhf1;
                float inn = gi2[i] + bif2, hn = gh2[i] + bhf2;
                float rg = 1.f / (1.f + expf(-(ir + hr)));
                float ug = 1.f / (1.f + expf(-(iz + hz)));
                float nn = tanhf(inn + rg * hn);
                float hp = prevf[(size_t)row * 128 + f];
                hnew[(size_t)row * 128 + f] = (1.f - ug) * nn + ug * hp;
            }
        }
    }
}

// transpose+cast fp32->bf16: dst[n*128+kk] = src[(rowoff+kk)*ld + n]
__global__ void transp_k(const float* __restrict__ src, bf16_t* __restrict__ dst,
                         int cols, int ld, int rowoff)
{
    int i = blockIdx.x * blockDim.x + threadIdx.x;
    if (i >= cols * 128) return;
    int n = i >> 7, kk = i & 127;
    dst[i] = (bf16_t)src[(size_t)(rowoff + kk) * ld + n];
}

// fp32 -> bf16 copy (element offset off0 into src)
__global__ void cvtb_k(const float* __restrict__ src, size_t off0,
                       bf16_t* __restrict__ dst, int n)
{
    for (int i = blockIdx.x * blockDim.x + threadIdx.x; i < n; i += gridDim.x * blockDim.x)
        dst[i] = (bf16_t)src[off0 + (size_t)i];
}

// meta: [0]=tmin bits [1]=K [2]=B [3]=above [4]=needInBin [5]=TL [6]=above2
//       [7]=need_eq [8]=eqCount
// Fused init: meta + bmeta + hist1 + hist2 + cnt + deg in one launch.
__global__ void initall(unsigned* meta, unsigned* bmeta, unsigned* hist1,
                        unsigned* hist2, unsigned* cnt, float* deg, int N, int k)
{
    int i = blockIdx.x * blockDim.x + threadIdx.x;
    int stride = gridDim.x * blockDim.x;
    if (i == 0) { meta[0] = 0x7f800000u; meta[1] = (unsigned)k; meta[8] = 0u; }
    if (i < 64) bmeta[i] = 0u;
    for (int j = i; j < 65536; j += stride) { hist1[j] = 0u; hist2[j] = 0u; }
    for (int j = i; j < N + 1; j += stride) cnt[j] = 0u;
    for (int j = i; j < N; j += stride) deg[j] = 1.0f;
}

__global__ void tmin_k(const float* __restrict__ et, unsigned* meta, int E)
{
    __shared__ float sred[4];
    int i = blockIdx.x * blockDim.x + threadIdx.x;
    int stride = gridDim.x * blockDim.x;
    float v = 1e30f;
    for (; i < E; i += stride) v = fminf(v, et[i]);
    for (int off = 32; off; off >>= 1) v = fminf(v, __shfl_down(v, off, 64));
    int wave = threadIdx.x >> 6, lane = threadIdx.x & 63;
    if (lane == 0) sred[wave] = v;
    __syncthreads();
    if (threadIdx.x == 0) {
        v = fminf(fminf(sred[0], sred[1]), fminf(sred[2], sred[3]));
        atomicMin(meta + 0, __float_as_uint(v));
    }
}

// bmeta: [0..3]=bcnt [4..8]=bofs [9..12]=cur   (fallback path only)
__global__ void bcount_k(const int* __restrict__ ei, unsigned* bmeta, int E, int Nh, int N)
{
    __shared__ unsigned sc[4];
    int tid = threadIdx.x;
    if (tid < 4) sc[tid] = 0;
    __syncthreads();
    int e = blockIdx.x * blockDim.x + tid;
    int b = -1;
    if (e < E) {
        int s = clampi(ei[e], N), d = clampi(ei[E + e], N);
        b = (s >= Nh ? 2 : 0) + (d >= Nh ? 1 : 0);
    }
    int lane = tid & 63;
#pragma unroll
    for (int bb = 0; bb < 4; ++bb) {
        unsigned long long m = __ballot(b == bb);
        if (lane == 0 && m) atomicAdd(sc + bb, (unsigned)__popcll(m));
    }
    __syncthreads();
    if (tid < 4 && sc[tid]) atomicAdd(bmeta + tid, sc[tid]);
}

__global__ void bscan_k(unsigned* bmeta)
{
    if (threadIdx.x == 0 && blockIdx.x == 0) {
        bmeta[4] = 0;
        for (int b = 0; b < 4; ++b) {
            bmeta[5 + b] = bmeta[4 + b] + bmeta[b];
            bmeta[9 + b] = bmeta[4 + b];
        }
    }
}

__global__ void bfill_k(const int* __restrict__ ei, unsigned* bmeta,
                        unsigned* __restrict__ elist, int E, int Nh, int N)
{
    __shared__ unsigned scount[4];
    __shared__ unsigned sbase[4];
    int tid = threadIdx.x;
    if (tid < 4) scount[tid] = 0;
    __syncthreads();
    int e = blockIdx.x * blockDim.x + tid;
    int b = -1;
    if (e < E) {
        int s = clampi(ei[e], N), d = clampi(ei[E + e], N);
        b = (s >= Nh ? 2 : 0) + (d >= Nh ? 1 : 0);
    }
    int lane = tid & 63;
    unsigned myofs = 0;
#pragma unroll
    for (int bb = 0; bb < 4; ++bb) {
        unsigned long long m = __ballot(b == bb);
        unsigned wb = 0;
        if (lane == 0 && m) wb = atomicAdd(scount + bb, (unsigned)__popcll(m));
        wb = __shfl(wb, 0, 64);
        if (b == bb) myofs = wb + (unsigned)__popcll(m & ((1ull << lane) - 1ull));
    }
    __syncthreads();
    if (tid < 4) sbase[tid] = scount[tid] ? atomicAdd(bmeta + 9 + tid, scount[tid]) : 0u;
    __syncthreads();
    if (b >= 0) elist[sbase[b] + myofs] = (unsigned)e;
}

// ---------------------------------------------------------------------------
// Wave-private fp32 GEMM: each wave owns a 32-row x 128-col tile; A staged in
// per-wave LDS (same-wave ds ordering, NO barriers); B (weights) read from
// L2 per k-step. 4-5 waves/SIMD resident, no cross-wave stalls.
// Per-output k-ascending fp32 order == previous kernel -> bit-identical out.
// ---------------------------------------------------------------------------
__global__ __launch_bounds__(256, 4) void proj2w(const float* __restrict__ prevf,
        const float* __restrict__ Wflat, float* __restrict__ out, int rows, int base)
{
    __shared__ float sP[4][16][36];
    int wave = threadIdx.x >> 6, lane = threadIdx.x & 63;
    int rbase = blockIdx.x * 128 + wave * 32;
    if (rbase >= rows) return;
    int tx = lane & 15, eg = lane >> 4;
    int kk = lane & 15, e0 = (lane >> 4) * 8;
    float acc[8][8];
#pragma unroll
    for (int i = 0; i < 8; ++i)
#pragma unroll
        for (int j = 0; j < 8; ++j) acc[i][j] = 0.f;
    for (int kc = 0; kc < 128; kc += 16) {
        float tmp[8];
#pragma unroll
        for (int i = 0; i < 8; ++i) {
            int rr = rbase + e0 + i; if (rr > rows - 1) rr = rows - 1;
            tmp[i] = prevf[(size_t)(base + rr) * 128 + kc + kk];
        }
#pragma unroll
        for (int i = 0; i < 8; ++i) sP[wave][kk][e0 + i] = tmp[i];
        asm volatile("" ::: "memory");
#pragma unroll
        for (int r = 0; r < 16; ++r) {
            f32x4 a0 = *(const f32x4*)&sP[wave][r][eg * 8];
            f32x4 a1 = *(const f32x4*)&sP[wave][r][eg * 8 + 4];
            f32x4 b0 = *(const f32x4*)&Wflat[(size_t)(kc + r) * 128 + tx * 4];
            f32x4 b1 = *(const f32x4*)&Wflat[(size_t)(kc + r) * 128 + 64 + tx * 4];
#pragma unroll
            for (int i = 0; i < 8; ++i) {
                float ae = i < 4 ? a0[i] : a1[i - 4];
#pragma unroll
                for (int j = 0; j < 4; ++j) {
                    acc[i][j]     = fmaf(ae, b0[j], acc[i][j]);
                    acc[i][j + 4] = fmaf(ae, b1[j], acc[i][j + 4]);
                }
            }
        }
        asm volatile("" ::: "memory");
    }
#pragma unroll
    for (int i = 0; i < 8; ++i) {
        int row = rbase + eg * 8 + i;
        if (row < rows) {
            f32x4 o0, o1;
#pragma unroll
            for (int j = 0; j < 4; ++j) { o0[j] = acc[i][j]; o1[j] = acc[i][j + 4]; }
            *(f32x4*)&out[(size_t)row * 128 + tx * 4] = o0;
            *(f32x4*)&out[(size_t)row * 128 + 64 + tx * 4] = o1;
        }
    }
}

// ---------------------------------------------------------------------------
// Wave-private z-pass: 32 edges per wave, TE=cos staged per-wave in LDS, wc
// from L2, no barriers. Epilogue: +A[s]+B[d]+bias, relu-dot ws2, identical
// reduction tree -> z bit-identical to previous rounds.
// ---------------------------------------------------------------------------
__global__ __launch_bounds__(256, 4) void zgemmw(
        const float* __restrict__ et, const int* __restrict__ ei,
        const unsigned* __restrict__ elist, const unsigned* __restrict__ bmeta, int b,
        int soff, int doff,
        const float* __restrict__ Ah, const float* __restrict__ Bh,
        const float* __restrict__ wtime, const float* __restrict__ btime,
        const float* __restrict__ wc, const float* __restrict__ bs1,
        const float* __restrict__ ws2, const float* __restrict__ bs2,
        const unsigned* __restrict__ meta,
        float* __restrict__ z, unsigned* __restrict__ hist1, int E, int N)
{
    unsigned lo = 0, hi = (unsigned)E;
    if (b >= 0) { lo = bmeta[4 + b]; hi = bmeta[5 + b]; }
    int wave = threadIdx.x >> 6, lane = threadIdx.x & 63;
    unsigned ebase = (unsigned)blockIdx.x * 128u + (unsigned)wave * 32u;
    if (ebase >= hi - lo) return;
    __shared__ float sT[4][32];
    __shared__ int sS[4][32], sD[4][32];
    __shared__ unsigned sE[4][32];
    __shared__ float sC[4][16][36];
    if (lane < 32) {
        float tmin = __uint_as_float(meta[0]);
        unsigned slot = lo + ebase + (unsigned)lane;
        unsigned sl = slot < hi ? slot : hi - 1u;
        unsigned e = elist ? elist[sl] : sl;
        sE[wave][lane] = e;
        sT[wave][lane] = et[e] - tmin + 1.0f;
        sS[wave][lane] = clampi(ei[e], N) - soff;
        sD[wave][lane] = clampi(ei[E + e], N) - doff;
    }
    asm volatile("" ::: "memory");
    int tx = lane & 15, eg = lane >> 4;
    int kk = lane & 15, e0 = (lane >> 4) * 8;
    float tv[8];
#pragma unroll
    for (int i = 0; i < 8; ++i) tv[i] = sT[wave][e0 + i];
    float acc[8][8];
#pragma unroll
    for (int i = 0; i < 8; ++i)
#pragma unroll
        for (int j = 0; j < 8; ++j) acc[i][j] = 0.f;
    for (int kc = 0; kc < 128; kc += 16) {
        float wt = wtime[kc + kk], bt = btime[kc + kk];
        float cv[8];
#pragma unroll
        for (int i = 0; i < 8; ++i) cv[i] = cosf(tv[i] * wt + bt);
#pragma unroll
        for (int i = 0; i < 8; ++i) sC[wave][kk][e0 + i] = cv[i];
        asm volatile("" ::: "memory");
#pragma unroll
        for (int r = 0; r < 16; ++r) {
            f32x4 a0 = *(const f32x4*)&sC[wave][r][eg * 8];
            f32x4 a1 = *(const f32x4*)&sC[wave][r][eg * 8 + 4];
            f32x4 b0 = *(const f32x4*)&wc[(size_t)(kc + r) * 128 + tx * 4];
            f32x4 b1 = *(const f32x4*)&wc[(size_t)(kc + r) * 128 + 64 + tx * 4];
#pragma unroll
            for (int i = 0; i < 8; ++i) {
                float ae = i < 4 ? a0[i] : a1[i - 4];
#pragma unroll
                for (int j = 0; j < 4; ++j) {
                    acc[i][j]     = fmaf(ae, b0[j], acc[i][j]);
                    acc[i][j + 4] = fmaf(ae, b1[j], acc[i][j + 4]);
                }
            }
        }
        asm volatile("" ::: "memory");
    }
    // epilogue: lane covers f = tx*4+j (and 64+tx*4+j), edges eg*8+i
    f32x4 bb0 = *(const f32x4*)&bs1[tx * 4];
    f32x4 bb1 = *(const f32x4*)&bs1[64 + tx * 4];
    f32x4 w20 = *(const f32x4*)&ws2[tx * 4];
    f32x4 w21 = *(const f32x4*)&ws2[64 + tx * 4];
    float myv = 0.f;
#pragma unroll
    for (int i = 0; i < 8; ++i) {
        int r = eg * 8 + i;
        int s = sS[wave][r], d = sD[wave][r];
        const float* As = Ah + (size_t)s * 128;
        const float* Bd = Bh + (size_t)d * 128;
        f32x4 A0 = *(const f32x4*)&As[tx * 4];
        f32x4 A1 = *(const f32x4*)&As[64 + tx * 4];
        f32x4 B0 = *(const f32x4*)&Bd[tx * 4];
        f32x4 B1 = *(const f32x4*)&Bd[64 + tx * 4];
        float v[4];
#pragma unroll
        for (int j = 0; j < 4; ++j) {
            float p0 = acc[i][j] + ((A0[j] + B0[j]) + bb0[j]);
            float p1 = acc[i][j + 4] + ((A1[j] + B1[j]) + bb1[j]);
            v[j] = fmaxf(p0, 0.f) * w20[j] + fmaxf(p1, 0.f) * w21[j];
        }
#pragma unroll
        for (int j = 0; j < 4; ++j) {
            v[j] += __shfl_xor(v[j], 8, 64);
            v[j] += __shfl_xor(v[j], 4, 64);
            v[j] += __shfl_xor(v[j], 2, 64);
            v[j] += __shfl_xor(v[j], 1, 64);
        }
        float vv = (v[0] + v[2]) + (v[1] + v[3]);
        if (tx == i) myv = vv;
    }
    if (tx < 8) {
        int r = eg * 8 + tx;
        unsigned slot = lo + ebase + (unsigned)r;
        if (slot < hi) {
            float b2 = bs2[0];
            float zv = 1.f / (1.f + expf(-(myv + b2)));
            z[sE[wave][r]] = zv;
            atomicAdd(hist1 + (__float_as_uint(zv) >> 16), 1u);
        }
    }
}

__global__ __launch_bounds__(1024) void scank(const unsigned* __restrict__ hist,
                                              unsigned* meta, int kIdx, int outIdx)
{
    __shared__ unsigned s[1024];
    int t = threadIdx.x;
    unsigned K = meta[kIdx];
    unsigned sum = 0;
    for (int i = 0; i < 64; ++i) sum += hist[t * 64 + i];
    s[t] = sum;
    __syncthreads();
    for (int off = 1; off < 1024; off <<= 1) {
        unsigned add = (t + off < 1024) ? s[t + off] : 0u;
        __syncthreads();
        s[t] += add;
        __syncthreads();
    }
    unsigned mine = s[t];
    unsigned after = (t < 1023) ? s[t + 1] : 0u;
    if (mine >= K && after < K) {
        unsigned cum = after;
        for (int b = 63; b >= 0; --b) {
            unsigned c = hist[t * 64 + b];
            cum += c;
            if (cum >= K) {
                meta[outIdx] = (unsigned)(t * 64 + b);
                meta[outIdx + 1] = cum - c;
                meta[outIdx + 2] = K - (cum - c);
                break;
            }
        }
    }
}

__global__ void pass2(const float* __restrict__ z, const unsigned* __restrict__ meta,
                      unsigned* hist2, int E)
{
    int e = blockIdx.x * blockDim.x + threadIdx.x;
    if (e >= E) return;
    unsigned u = __float_as_uint(z[e]);
    if ((u >> 16) == meta[2]) atomicAdd(hist2 + (u & 0xffffu), 1u);
}

__global__ void pass3(const float* __restrict__ z, unsigned* meta,
                      unsigned char* keep, unsigned* eql, int E)
{
    int e = blockIdx.x * blockDim.x + threadIdx.x;
    if (e >= E) return;
    unsigned u = __float_as_uint(z[e]);
    unsigned T = (meta[2] << 16) | (meta[5] & 0xffffu);
    keep[e] = (u > T) ? 1 : 0;
    if (u == T) {
        unsigned slot = atomicAdd(meta + 8, 1u);
        if (slot < 4096u) eql[slot] = (unsigned)e;
    }
}

__global__ void eqres(const unsigned* __restrict__ meta, const unsigned* __restrict__ eql,
                      unsigned char* keep)
{
    __shared__ unsigned list[4096];
    unsigned c = meta[8]; if (c > 4096u) c = 4096u;
    unsigned need = meta[7];
    for (unsigned i = threadIdx.x; i < c; i += blockDim.x) list[i] = eql[i];
    __syncthreads();
    for (unsigned i = threadIdx.x; i < c; i += blockDim.x) {
        unsigned rank = 0;
        for (unsigned j = 0; j < c; ++j) rank += (list[j] < list[i]) ? 1u : 0u;
        if (rank < need) keep[list[i]] = 1;
    }
}

__global__ void degsc(const int* __restrict__ ei, const float* __restrict__ z,
                      const unsigned char* __restrict__ keep, float* deg, int E, int N)
{
    int e = blockIdx.x * blockDim.x + threadIdx.x;
    if (e >= E) return;
    if (keep[e]) atomicAdd(deg + clampi(ei[E + e], N), z[e]);
}

__global__ void dinv_k(float* deg, float* selfn, int N)
{
    int i = blockIdx.x * blockDim.x + threadIdx.x;
    if (i >= N) return;
    float d = deg[i];
    float di = 1.0f / sqrtf(d);   // deg >= 1 (self-loop weight 1)
    deg[i] = di;
    selfn[i] = di * di;
}

__global__ void normcnt(const int* __restrict__ ei, const float* __restrict__ z,
                        const unsigned char* __restrict__ keep, const float* __restrict__ dinv,
                        float* normv, unsigned* cnt, int E, int N)
{
    int e = blockIdx.x * blockDim.x + threadIdx.x;
    if (e >= E) return;
    if (keep[e]) {
        int s = clampi(ei[e], N), d = clampi(ei[E + e], N);
        normv[e] = dinv[s] * z[e] * dinv[d];
        atomicAdd(cnt + d, 1u);
    } else {
        normv[e] = 0.f;
    }
}

__global__ __launch_bounds__(1024) void scan_n(unsigned* cnt, unsigned* fill, int N)
{
    __shared__ unsigned s[1024];
    int t = threadIdx.x;
    int per = (N + 1023) >> 10;
    int lo = t * per; if (lo > N) lo = N;
    int hi = lo + per; if (hi > N) hi = N;
    unsigned sum = 0;
    for (int i = lo; i < hi; ++i) sum += cnt[i];
    s[t] = sum;
    __syncthreads();
    for (int off = 1; off < 1024; off <<= 1) {
        unsigned add = (t >= off) ? s[t - off] : 0u;
        __syncthreads();
        s[t] += add;
        __syncthreads();
    }
    unsigned run = (t > 0) ? s[t - 1] : 0u;
    for (int i = lo; i < hi; ++i) {
        unsigned c = cnt[i];
        cnt[i] = run; fill[i] = run;
        run += c;
    }
    if (t == 1023) cnt[N] = run;
}

__global__ void fillk(const int* __restrict__ ei, const unsigned char* __restrict__ keep,
                      unsigned* fill, unsigned* csr, int E, int N)
{
    int e = blockIdx.x * blockDim.x + threadIdx.x;
    if (e >= E) return;
    if (keep[e]) {
        unsigned p = atomicAdd(fill + clampi(ei[E + e], N), 1u);
        csr[p] = (unsigned)e;
    }
}

// GCN aggregation: hout[n] = (relu?)( bias + selfn[n]*m[n] + sum_e norm[e]*m[src[e]] )
__global__ __launch_bounds__(256) void agg_k(const bf16_t* __restrict__ m,
        const int* __restrict__ ei, const float* __restrict__ normv,
        const unsigned* __restrict__ ofs, const unsigned* __restrict__ csr,
        const float* __restrict__ selfn, const float* __restrict__ bias,
        float* __restrict__ hout, bf16_t* __restrict__ houtb, int N, int E, int dorelu)
{
    int wave = threadIdx.x >> 6, lane = threadIdx.x & 63;
    int n = blockIdx.x * 4 + wave;
    if (n >= N) return;
    int f = 2 * lane;
    float sn = selfn[n];
    bf16x2 mv = *(const bf16x2*)(m + (size_t)n * 128 + f);
    float a0 = bias[f] + sn * (float)mv[0];
    float a1 = bias[f + 1] + sn * (float)mv[1];
    unsigned lo = ofs[n], hi = ofs[n + 1];
    unsigned deg = hi - lo;
    unsigned cap = deg < 64u ? deg : 64u;
    int s_l = 0; float w_l = 0.f;
    if (lane < (int)cap) {
        unsigned e = csr[lo + lane];
        s_l = clampi(ei[e], N);
        w_l = normv[e];
    }
    for (unsigned j = 0; j < cap; ++j) {
        int s = __shfl(s_l, (int)j, 64);
        float w = __shfl(w_l, (int)j, 64);
        bf16x2 v = *(const bf16x2*)(m + (size_t)s * 128 + f);
        a0 = fmaf(w, (float)v[0], a0);
        a1 = fmaf(w, (float)v[1], a1);
    }
    for (unsigned idx = lo + 64; idx < hi; ++idx) {
        unsigned e = csr[idx];
        int s = clampi(ei[e], N);
        float w = normv[e];
        bf16x2 v = *(const bf16x2*)(m + (size_t)s * 128 + f);
        a0 = fmaf(w, (float)v[0], a0);
        a1 = fmaf(w, (float)v[1], a1);
    }
    if (dorelu) { a0 = fmaxf(a0, 0.f); a1 = fmaxf(a1, 0.f); }
    f32x2 o; o[0] = a0; o[1] = a1;
    *(f32x2*)(hout + (size_t)n * 128 + f) = o;
    if (houtb) {
        bf16x2 ob; ob[0] = (bf16_t)a0; ob[1] = (bf16_t)a1;
        *(bf16x2*)(houtb + (size_t)n * 128 + f) = ob;
    }
}

__global__ __launch_bounds__(256) void decode_k(const int* __restrict__ eli,
        const float* __restrict__ hnew, const float* __restrict__ wdec,
        const float* __restrict__ bdec, float* __restrict__ pred, int L, int N)
{
    int wave = threadIdx.x >> 6, lane = threadIdx.x & 63;
    int l = blockIdx.x * 4 + wave;
    if (l >= L) return;
    int a = clampi(eli[l], N), b = clampi(eli[L + l], N);
    f32x2 ha = *(const f32x2*)(hnew + (size_t)a * 128 + 2 * lane);
    f32x2 hb = *(const f32x2*)(hnew + (size_t)b * 128 + 2 * lane);
    f32x2 w  = *(const f32x2*)(wdec + 2 * lane);
    float acc = ha[0] * hb[0] * w[0] + ha[1] * hb[1] * w[1];
    for (int off = 32; off; off >>= 1) acc += __shfl_down(acc, off, 64);
    if (lane == 0) pred[l] = acc + bdec[0];
}

// ---------------------------------------------------------------------------
extern "C" void kernel_launch(void* const* d_in, const int* in_sizes, int n_in,
                              void* d_out, int out_size, void* d_ws, size_t ws_size,
                              hipStream_t stream)
{
    (void)n_in; (void)out_size;
    const float* x      = (const float*)d_in[0];
    const int*   ei     = (const int*)d_in[1];
    const int*   eli    = (const int*)d_in[2];
    const float* etime  = (const float*)d_in[3];
    const float* prev   = (const float*)d_in[4];
    const float* w_mlp  = (const float*)d_in[5];
    const float* b_mlp  = (const float*)d_in[6];
    const float* w_time = (const float*)d_in[7];
    const float* b_time = (const float*)d_in[8];
    const float* w_s1   = (const float*)d_in[9];
    const float* b_s1   = (const float*)d_in[10];
    const float* w_s2   = (const float*)d_in[11];
    const float* b_s2   = (const float*)d_in[12];
    const float* gcn_w  = (const float*)d_in[13];
    const float* gcn_b  = (const float*)d_in[14];
    const float* gru_wi = (const float*)d_in[15];
    const float* gru_wh = (const float*)d_in[16];
    const float* gru_bi = (const float*)d_in[17];
    const float* gru_bh = (const float*)d_in[18];
    const float* w_dec  = (const float*)d_in[19];
    const float* b_dec  = (const float*)d_in[20];

    const int E  = in_sizes[3];
    const int N  = in_sizes[0] / 128;
    const int L  = in_sizes[2] / 2;
    const int K  = (int)(0.8 * (double)E);
    const int Nh = (N + 1) / 2;

    char* wsp = (char*)d_ws;
    size_t off = 0;
    auto alloc = [&](size_t bytes) -> void* {
        void* p = wsp + off;
        off += (bytes + 255) & ~(size_t)255;
        return p;
    };
    unsigned* meta  = (unsigned*)alloc(64 * 4);
    unsigned* bmeta = (unsigned*)alloc(64 * 4);
    unsigned* elist = (unsigned*)alloc((size_t)E * 4);
    unsigned* eql   = (unsigned*)alloc(4096 * 4);
    unsigned* hist1 = (unsigned*)alloc(65536 * 4);
    unsigned* hist2 = (unsigned*)alloc(65536 * 4);
    unsigned* cnt   = (unsigned*)alloc((size_t)(N + 1) * 4);
    unsigned* fill  = (unsigned*)alloc((size_t)N * 4);
    float* deg      = (float*)alloc((size_t)N * 4);
    float* selfn    = (float*)alloc((size_t)N * 4);
    float* zbuf     = (float*)alloc((size_t)E * 4);
    unsigned char* keep = (unsigned char*)alloc((size_t)E);
    float* normv    = (float*)alloc((size_t)E * 4);
    unsigned* csr   = (unsigned*)alloc((size_t)E * 4);
    // bf16 transposed weights for MFMA
    bf16_t* wmlpT = (bf16_t*)alloc(128 * 128 * 2);
    bf16_t* g0T   = (bf16_t*)alloc(128 * 128 * 2);
    bf16_t* g1T   = (bf16_t*)alloc(128 * 128 * 2);
    bf16_t* wiT   = (bf16_t*)alloc(384 * 128 * 2);
    bf16_t* whT   = (bf16_t*)alloc(384 * 128 * 2);

    // Projection buffers: full [N,128] fp32 A and B if workspace allows
    // (single z pass, no bucketing); else half-size slots with 4 bucket phases.
    size_t fullBytes = (size_t)N * 128 * 4;
    size_t halfBytes = (size_t)Nh * 128 * 4;
    bool full = (off + 2 * ((fullBytes + 255) & ~(size_t)255)) <= ws_size;
    char* slot0; char* slot1;
    float* Ahalf; float* Bhalf;
    if (full) {
        slot0 = (char*)alloc(fullBytes);
        slot1 = (char*)alloc(fullBytes);
        Ahalf = (float*)slot0;            // full A
        Bhalf = (float*)slot1;            // full B
    } else {
        slot0 = (char*)alloc(halfBytes);
        slot1 = (char*)alloc(halfBytes);
        Ahalf = (float*)slot0;
        Bhalf = (float*)slot1;
    }
    bf16_t* xbf   = (bf16_t*)slot0;      // bf16 copy of x / h
    bf16_t* mbuf  = (bf16_t*)slot1;

    // fp32 outputs: pred [L], h_new [N,128]. h_new region doubles as hb (fp32 h).
    float* out_pred = (float*)d_out;
    float* hnew     = (float*)d_out + L;
    float* hb       = hnew;

    // ---- init (fused) ----
    initall<<<1024, 256, 0, stream>>>(meta, bmeta, hist1, hist2, cnt, deg, N, K);

    // ---- bf16 transposed weights for MFMA ----
    transp_k<<<64, 256, 0, stream>>>(w_mlp, wmlpT, 128, 128, 0);
    transp_k<<<64, 256, 0, stream>>>(gcn_w, g0T, 128, 128, 0);
    transp_k<<<64, 256, 0, stream>>>(gcn_w, g1T, 128, 128, 128);
    transp_k<<<192, 256, 0, stream>>>(gru_wi, wiT, 384, 384, 0);
    transp_k<<<192, 256, 0, stream>>>(gru_wh, whT, 384, 384, 0);

    tmin_k<<<512, 256, 0, stream>>>(etime, meta, E);

    // ---- z pass ----
    const int zgrid = (E + 127) / 128;
    const float* wc = w_s1 + 256 * 128;
    if (full) {
        proj2w<<<(N + 127) / 128, 256, 0, stream>>>(prev, w_s1, Ahalf, N, 0);
        proj2w<<<(N + 127) / 128, 256, 0, stream>>>(prev, w_s1 + 128 * 128, Bhalf, N, 0);
        zgemmw<<<zgrid, 256, 0, stream>>>(etime, ei, (const unsigned*)nullptr, bmeta, -1,
                0, 0, Ahalf, Bhalf, w_time, b_time, wc, b_s1, w_s2, b_s2,
                meta, zbuf, hist1, E, N);
    } else {
        // bucket edges by (s>=Nh, d>=Nh)
        bcount_k<<<(E + 255) / 256, 256, 0, stream>>>(ei, bmeta, E, Nh, N);
        bscan_k<<<1, 64, 0, stream>>>(bmeta);
        bfill_k<<<(E + 255) / 256, 256, 0, stream>>>(ei, bmeta, elist, E, Nh, N);
        const int NA0 = Nh, NA1 = N - Nh;
        auto zlaunch = [&](int b, int so, int doo) {
            zgemmw<<<zgrid, 256, 0, stream>>>(etime, ei, elist, bmeta, b, so, doo,
                    Ahalf, Bhalf, w_time, b_time, wc, b_s1, w_s2, b_s2,
                    meta, zbuf, hist1, E, N);
        };
        proj2w<<<(NA0 + 127) / 128, 256, 0, stream>>>(prev, w_s1, Ahalf, NA0, 0);
        proj2w<<<(NA0 + 127) / 128, 256, 0, stream>>>(prev, w_s1 + 128 * 128, Bhalf, NA0, 0);
        zlaunch(0, 0, 0);
        proj2w<<<(NA1 + 127) / 128, 256, 0, stream>>>(prev, w_s1 + 128 * 128, Bhalf, NA1, Nh);
        zlaunch(1, 0, Nh);
        proj2w<<<(NA1 + 127) / 128, 256, 0, stream>>>(prev, w_s1, Ahalf, NA1, Nh);
        zlaunch(3, Nh, Nh);
        proj2w<<<(NA0 + 127) / 128, 256, 0, stream>>>(prev, w_s1 + 128 * 128, Bhalf, NA0, 0);
        zlaunch(2, Nh, 0);
    }

    // ---- exact top-k radix select ----
    scank<<<1, 1024, 0, stream>>>(hist1, meta, 1, 2);
    pass2<<<(E + 255) / 256, 256, 0, stream>>>(zbuf, meta, hist2, E);
    scank<<<1, 1024, 0, stream>>>(hist2, meta, 4, 5);
    pass3<<<(E + 255) / 256, 256, 0, stream>>>(zbuf, meta, keep, eql, E);
    eqres<<<1, 256, 0, stream>>>(meta, eql, keep);

    // ---- degrees / norms / CSR ----
    degsc<<<(E + 255) / 256, 256, 0, stream>>>(ei, zbuf, keep, deg, E, N);
    dinv_k<<<(N + 255) / 256, 256, 0, stream>>>(deg, selfn, N);
    normcnt<<<(E + 255) / 256, 256, 0, stream>>>(ei, zbuf, keep, deg, normv, cnt, E, N);
    scan_n<<<1, 1024, 0, stream>>>(cnt, fill, N);
    fillk<<<(E + 255) / 256, 256, 0, stream>>>(ei, keep, fill, csr, E, N);

    // ---- h0 = relu(x @ w_mlp + b_mlp): fp32 in d_out, bf16 fused (in-place) ----
    cvtb_k<<<2048, 256, 0, stream>>>(x, 0, xbf, N * 128);
    gemm128<128><<<(N + 63) / 64, 256, 0, stream>>>(xbf, wmlpT, b_mlp, hb, xbf, N, 1);

    // ---- GCN layers (h fp32 in d_out; bf16 copies fused into epilogues) ----
    gemm128<128><<<(N + 63) / 64, 256, 0, stream>>>(xbf, g0T, nullptr, nullptr, mbuf, N, 0);
    agg_k<<<(N + 3) / 4, 256, 0, stream>>>(mbuf, ei, normv, cnt, csr, selfn, gcn_b, hb, xbf, N, E, 1);
    gemm128<128><<<(N + 63) / 64, 256, 0, stream>>>(xbf, g1T, nullptr, nullptr, mbuf, N, 0);
    agg_k<<<(N + 3) / 4, 256, 0, stream>>>(mbuf, ei, normv, cnt, csr, selfn, gcn_b + 128, hb, xbf, N, E, 0);

    // ---- fused GRU: h_new = gate(xbf@wiT+bi, prev@whT+bh, prev) ----
    gru_k<<<(N + 63) / 64, 256, 0, stream>>>(xbf, prev, wiT, whT, gru_bi, gru_bh, hnew, N);

    // ---- link decoder (fp32) ----
    decode_k<<<(L + 3) / 4, 256, 0, stream>>>(eli, hnew, w_dec, b_dec, out_pred, L, N);
}

// Round 5
// 1478.643 us; speedup vs baseline: 1.1290x; 1.1290x over previous
//
#include <hip/hip_runtime.h>
#include <hip/hip_bf16.h>
#include <math.h>

typedef __bf16 bf16_t;
typedef bf16_t bf16x8 __attribute__((ext_vector_type(8)));
typedef bf16_t bf16x2 __attribute__((ext_vector_type(2)));
typedef float  f32x4  __attribute__((ext_vector_type(4)));
typedef float  f32x2  __attribute__((ext_vector_type(2)));

__device__ __forceinline__ int clampi(int v, int n) {
    return v < 0 ? 0 : (v > n - 1 ? n - 1 : v);
}

// ---------------------------------------------------------------------------
// bf16 MFMA GEMM: C[M,NC] = A[M,128] @ BT[NC,128]^T (+fp32 bias, relu)
// In-place Cb==A is safe: each wave reads only its own 16-row strip before
// writing it.
// ---------------------------------------------------------------------------
template<int NC>
__global__ __launch_bounds__(256) void gemm128(const bf16_t* __restrict__ A,
        const bf16_t* __restrict__ BT, const float* __restrict__ bias,
        float* __restrict__ Cf, bf16_t* __restrict__ Cb, int M, int dorelu)
{
    constexpr int NT = NC / 16;
    int wave = threadIdx.x >> 6, lane = threadIdx.x & 63;
    int mbase = (blockIdx.x * 4 + wave) * 16;
    if (mbase >= M) return;
    int r = lane & 15, q = lane >> 4;
    int arow = mbase + r; if (arow > M - 1) arow = M - 1;
    f32x4 acc[NT];
#pragma unroll
    for (int t = 0; t < NT; ++t) acc[t] = f32x4{0.f, 0.f, 0.f, 0.f};
    const bf16_t* aptr = A + (size_t)arow * 128 + q * 8;
#pragma unroll
    for (int kk = 0; kk < 4; ++kk) {
        bf16x8 af = *(const bf16x8*)(aptr + kk * 32);
#pragma unroll
        for (int t = 0; t < NT; ++t) {
            bf16x8 bfg = *(const bf16x8*)(BT + (size_t)(t * 16 + r) * 128 + kk * 32 + q * 8);
            acc[t] = __builtin_amdgcn_mfma_f32_16x16x32_bf16(af, bfg, acc[t], 0, 0, 0);
        }
    }
#pragma unroll
    for (int t = 0; t < NT; ++t) {
#pragma unroll
        for (int i = 0; i < 4; ++i) {
            int row = mbase + q * 4 + i;
            if (row < M) {
                int col = t * 16 + r;
                float v = acc[t][i];
                if (bias) v += bias[col];
                if (dorelu) v = fmaxf(v, 0.f);
                if (Cf) Cf[(size_t)row * NC + col] = v;
                if (Cb) Cb[(size_t)row * NC + col] = (bf16_t)v;
            }
        }
    }
}

// ---------------------------------------------------------------------------
// Fused GRU: per 16-row strip compute gi = xb@wiT+bi, gh = prev@whT+bh and
// the gate, writing h_new directly.
// ---------------------------------------------------------------------------
__global__ __launch_bounds__(256) void gru_k(const bf16_t* __restrict__ xb,
        const float* __restrict__ prevf, const bf16_t* __restrict__ wiT,
        const bf16_t* __restrict__ whT, const float* __restrict__ bi,
        const float* __restrict__ bh, float* __restrict__ hnew, int M)
{
    int wave = threadIdx.x >> 6, lane = threadIdx.x & 63;
    int mbase = (blockIdx.x * 4 + wave) * 16;
    if (mbase >= M) return;
    int r = lane & 15, q = lane >> 4;
    int arow = mbase + r; if (arow > M - 1) arow = M - 1;
    bf16x8 ax[4], ap[4];
#pragma unroll
    for (int kk = 0; kk < 4; ++kk) {
        ax[kk] = *(const bf16x8*)(xb + (size_t)arow * 128 + kk * 32 + q * 8);
        f32x4 p0 = *(const f32x4*)(prevf + (size_t)arow * 128 + kk * 32 + q * 8);
        f32x4 p1 = *(const f32x4*)(prevf + (size_t)arow * 128 + kk * 32 + q * 8 + 4);
        bf16x8 t;
#pragma unroll
        for (int j = 0; j < 4; ++j) { t[j] = (bf16_t)p0[j]; t[j + 4] = (bf16_t)p1[j]; }
        ap[kk] = t;
    }
#pragma unroll
    for (int t3 = 0; t3 < 8; ++t3) {
        f32x4 gi0{0.f,0.f,0.f,0.f}, gi1{0.f,0.f,0.f,0.f}, gi2{0.f,0.f,0.f,0.f};
        f32x4 gh0{0.f,0.f,0.f,0.f}, gh1{0.f,0.f,0.f,0.f}, gh2{0.f,0.f,0.f,0.f};
#pragma unroll
        for (int kk = 0; kk < 4; ++kk) {
            const bf16_t* wi = wiT + (size_t)(t3 * 16 + r) * 128 + kk * 32 + q * 8;
            const bf16_t* wh = whT + (size_t)(t3 * 16 + r) * 128 + kk * 32 + q * 8;
            gi0 = __builtin_amdgcn_mfma_f32_16x16x32_bf16(ax[kk], *(const bf16x8*)wi, gi0, 0, 0, 0);
            gi1 = __builtin_amdgcn_mfma_f32_16x16x32_bf16(ax[kk], *(const bf16x8*)(wi + 128 * 128), gi1, 0, 0, 0);
            gi2 = __builtin_amdgcn_mfma_f32_16x16x32_bf16(ax[kk], *(const bf16x8*)(wi + 256 * 128), gi2, 0, 0, 0);
            gh0 = __builtin_amdgcn_mfma_f32_16x16x32_bf16(ap[kk], *(const bf16x8*)wh, gh0, 0, 0, 0);
            gh1 = __builtin_amdgcn_mfma_f32_16x16x32_bf16(ap[kk], *(const bf16x8*)(wh + 128 * 128), gh1, 0, 0, 0);
            gh2 = __builtin_amdgcn_mfma_f32_16x16x32_bf16(ap[kk], *(const bf16x8*)(wh + 256 * 128), gh2, 0, 0, 0);
        }
        int f = t3 * 16 + r;
        float bif0 = bi[f], bif1 = bi[128 + f], bif2 = bi[256 + f];
        float bhf0 = bh[f], bhf1 = bh[128 + f], bhf2 = bh[256 + f];
#pragma unroll
        for (int i = 0; i < 4; ++i) {
            int row = mbase + q * 4 + i;
            if (row < M) {
                float ir = gi0[i] + bif0, hr = gh0[i] + bhf0;
                float iz = gi1[i] + bif1, hz = gh1[i] + bhf1;
                float inn = gi2[i] + bif2, hn = gh2[i] + bhf2;
                float rg = 1.f / (1.f + expf(-(ir + hr)));
                float ug = 1.f / (1.f + expf(-(iz + hz)));
                float nn = tanhf(inn + rg * hn);
                float hp = prevf[(size_t)row * 128 + f];
                hnew[(size_t)row * 128 + f] = (1.f - ug) * nn + ug * hp;
            }
        }
    }
}

// transpose+cast fp32->bf16: dst[n*128+kk] = src[(rowoff+kk)*ld + n]
__global__ void transp_k(const float* __restrict__ src, bf16_t* __restrict__ dst,
                         int cols, int ld, int rowoff)
{
    int i = blockIdx.x * blockDim.x + threadIdx.x;
    if (i >= cols * 128) return;
    int n = i >> 7, kk = i & 127;
    dst[i] = (bf16_t)src[(size_t)(rowoff + kk) * ld + n];
}

// fp32 -> bf16 copy (element offset off0 into src)
__global__ void cvtb_k(const float* __restrict__ src, size_t off0,
                       bf16_t* __restrict__ dst, int n)
{
    for (int i = blockIdx.x * blockDim.x + threadIdx.x; i < n; i += gridDim.x * blockDim.x)
        dst[i] = (bf16_t)src[off0 + (size_t)i];
}

// meta: [0]=tmin bits [1]=K [2]=B [3]=above [4]=needInBin [5]=TL [6]=above2
//       [7]=need_eq [8]=eqCount
// Fused init: meta + bmeta + hist1 + hist2 + cnt + deg in one launch.
__global__ void initall(unsigned* meta, unsigned* bmeta, unsigned* hist1,
                        unsigned* hist2, unsigned* cnt, float* deg, int N, int k)
{
    int i = blockIdx.x * blockDim.x + threadIdx.x;
    int stride = gridDim.x * blockDim.x;
    if (i == 0) { meta[0] = 0x7f800000u; meta[1] = (unsigned)k; meta[8] = 0u; }
    if (i < 64) bmeta[i] = 0u;
    for (int j = i; j < 65536; j += stride) { hist1[j] = 0u; hist2[j] = 0u; }
    for (int j = i; j < N + 1; j += stride) cnt[j] = 0u;
    for (int j = i; j < N; j += stride) deg[j] = 1.0f;
}

__global__ void tmin_k(const float* __restrict__ et, unsigned* meta, int E)
{
    __shared__ float sred[4];
    int i = blockIdx.x * blockDim.x + threadIdx.x;
    int stride = gridDim.x * blockDim.x;
    float v = 1e30f;
    for (; i < E; i += stride) v = fminf(v, et[i]);
    for (int off = 32; off; off >>= 1) v = fminf(v, __shfl_down(v, off, 64));
    int wave = threadIdx.x >> 6, lane = threadIdx.x & 63;
    if (lane == 0) sred[wave] = v;
    __syncthreads();
    if (threadIdx.x == 0) {
        v = fminf(fminf(sred[0], sred[1]), fminf(sred[2], sred[3]));
        atomicMin(meta + 0, __float_as_uint(v));
    }
}

// bmeta: [0..3]=bcnt [4..8]=bofs [9..12]=cur   (fallback path only)
__global__ void bcount_k(const int* __restrict__ ei, unsigned* bmeta, int E, int Nh, int N)
{
    __shared__ unsigned sc[4];
    int tid = threadIdx.x;
    if (tid < 4) sc[tid] = 0;
    __syncthreads();
    int e = blockIdx.x * blockDim.x + tid;
    int b = -1;
    if (e < E) {
        int s = clampi(ei[e], N), d = clampi(ei[E + e], N);
        b = (s >= Nh ? 2 : 0) + (d >= Nh ? 1 : 0);
    }
    int lane = tid & 63;
#pragma unroll
    for (int bb = 0; bb < 4; ++bb) {
        unsigned long long m = __ballot(b == bb);
        if (lane == 0 && m) atomicAdd(sc + bb, (unsigned)__popcll(m));
    }
    __syncthreads();
    if (tid < 4 && sc[tid]) atomicAdd(bmeta + tid, sc[tid]);
}

__global__ void bscan_k(unsigned* bmeta)
{
    if (threadIdx.x == 0 && blockIdx.x == 0) {
        bmeta[4] = 0;
        for (int b = 0; b < 4; ++b) {
            bmeta[5 + b] = bmeta[4 + b] + bmeta[b];
            bmeta[9 + b] = bmeta[4 + b];
        }
    }
}

__global__ void bfill_k(const int* __restrict__ ei, unsigned* bmeta,
                        unsigned* __restrict__ elist, int E, int Nh, int N)
{
    __shared__ unsigned scount[4];
    __shared__ unsigned sbase[4];
    int tid = threadIdx.x;
    if (tid < 4) scount[tid] = 0;
    __syncthreads();
    int e = blockIdx.x * blockDim.x + tid;
    int b = -1;
    if (e < E) {
        int s = clampi(ei[e], N), d = clampi(ei[E + e], N);
        b = (s >= Nh ? 2 : 0) + (d >= Nh ? 1 : 0);
    }
    int lane = tid & 63;
    unsigned myofs = 0;
#pragma unroll
    for (int bb = 0; bb < 4; ++bb) {
        unsigned long long m = __ballot(b == bb);
        unsigned wb = 0;
        if (lane == 0 && m) wb = atomicAdd(scount + bb, (unsigned)__popcll(m));
        wb = __shfl(wb, 0, 64);
        if (b == bb) myofs = wb + (unsigned)__popcll(m & ((1ull << lane) - 1ull));
    }
    __syncthreads();
    if (tid < 4) sbase[tid] = scount[tid] ? atomicAdd(bmeta + 9 + tid, scount[tid]) : 0u;
    __syncthreads();
    if (b >= 0) elist[sbase[b] + myofs] = (unsigned)e;
}

// ---------------------------------------------------------------------------
// Wave-private fp32 GEMM: each wave owns a 32-row x 128-col tile; A staged in
// per-wave LDS (same-wave ds ordering, NO barriers); B (weights) read from
// L1/L2 per k-step. __launch_bounds__(256,2): 256-VGPR budget so acc[8][8]
// stays in registers (the (256,4) variant spilled: VGPR=64, 438 MB scratch).
// ---------------------------------------------------------------------------
__global__ __launch_bounds__(256, 2) void proj2w(const float* __restrict__ prevf,
        const float* __restrict__ Wflat, float* __restrict__ out, int rows, int base)
{
    __shared__ float sP[4][16][36];
    int wave = threadIdx.x >> 6, lane = threadIdx.x & 63;
    int rbase = blockIdx.x * 128 + wave * 32;
    if (rbase >= rows) return;
    int tx = lane & 15, eg = lane >> 4;
    int kk = lane & 15, e0 = (lane >> 4) * 8;
    float acc[8][8];
#pragma unroll
    for (int i = 0; i < 8; ++i)
#pragma unroll
        for (int j = 0; j < 8; ++j) acc[i][j] = 0.f;
    for (int kc = 0; kc < 128; kc += 16) {
        float tmp[8];
#pragma unroll
        for (int i = 0; i < 8; ++i) {
            int rr = rbase + e0 + i; if (rr > rows - 1) rr = rows - 1;
            tmp[i] = prevf[(size_t)(base + rr) * 128 + kc + kk];
        }
#pragma unroll
        for (int i = 0; i < 8; ++i) sP[wave][kk][e0 + i] = tmp[i];
        asm volatile("" ::: "memory");
#pragma unroll
        for (int r = 0; r < 16; ++r) {
            f32x4 a0 = *(const f32x4*)&sP[wave][r][eg * 8];
            f32x4 a1 = *(const f32x4*)&sP[wave][r][eg * 8 + 4];
            f32x4 b0 = *(const f32x4*)&Wflat[(size_t)(kc + r) * 128 + tx * 4];
            f32x4 b1 = *(const f32x4*)&Wflat[(size_t)(kc + r) * 128 + 64 + tx * 4];
#pragma unroll
            for (int i = 0; i < 8; ++i) {
                float ae = i < 4 ? a0[i] : a1[i - 4];
#pragma unroll
                for (int j = 0; j < 4; ++j) {
                    acc[i][j]     = fmaf(ae, b0[j], acc[i][j]);
                    acc[i][j + 4] = fmaf(ae, b1[j], acc[i][j + 4]);
                }
            }
        }
        asm volatile("" ::: "memory");
    }
#pragma unroll
    for (int i = 0; i < 8; ++i) {
        int row = rbase + eg * 8 + i;
        if (row < rows) {
            f32x4 o0, o1;
#pragma unroll
            for (int j = 0; j < 4; ++j) { o0[j] = acc[i][j]; o1[j] = acc[i][j + 4]; }
            *(f32x4*)&out[(size_t)row * 128 + tx * 4] = o0;
            *(f32x4*)&out[(size_t)row * 128 + 64 + tx * 4] = o1;
        }
    }
}

// ---------------------------------------------------------------------------
// Wave-private z-pass: 32 edges per wave, TE=cos staged per-wave in LDS, wc
// from L1/L2, no barriers. (256,2) keeps acc in registers. Epilogue:
// +A[s]+B[d]+bias, relu-dot ws2, identical reduction tree -> z bit-identical.
// ---------------------------------------------------------------------------
__global__ __launch_bounds__(256, 2) void zgemmw(
        const float* __restrict__ et, const int* __restrict__ ei,
        const unsigned* __restrict__ elist, const unsigned* __restrict__ bmeta, int b,
        int soff, int doff,
        const float* __restrict__ Ah, const float* __restrict__ Bh,
        const float* __restrict__ wtime, const float* __restrict__ btime,
        const float* __restrict__ wc, const float* __restrict__ bs1,
        const float* __restrict__ ws2, const float* __restrict__ bs2,
        const unsigned* __restrict__ meta,
        float* __restrict__ z, unsigned* __restrict__ hist1, int E, int N)
{
    unsigned lo = 0, hi = (unsigned)E;
    if (b >= 0) { lo = bmeta[4 + b]; hi = bmeta[5 + b]; }
    int wave = threadIdx.x >> 6, lane = threadIdx.x & 63;
    unsigned ebase = (unsigned)blockIdx.x * 128u + (unsigned)wave * 32u;
    if (ebase >= hi - lo) return;
    __shared__ float sT[4][32];
    __shared__ int sS[4][32], sD[4][32];
    __shared__ unsigned sE[4][32];
    __shared__ float sC[4][16][36];
    if (lane < 32) {
        float tmin = __uint_as_float(meta[0]);
        unsigned slot = lo + ebase + (unsigned)lane;
        unsigned sl = slot < hi ? slot : hi - 1u;
        unsigned e = elist ? elist[sl] : sl;
        sE[wave][lane] = e;
        sT[wave][lane] = et[e] - tmin + 1.0f;
        sS[wave][lane] = clampi(ei[e], N) - soff;
        sD[wave][lane] = clampi(ei[E + e], N) - doff;
    }
    asm volatile("" ::: "memory");
    int tx = lane & 15, eg = lane >> 4;
    int kk = lane & 15, e0 = (lane >> 4) * 8;
    float tv[8];
#pragma unroll
    for (int i = 0; i < 8; ++i) tv[i] = sT[wave][e0 + i];
    float acc[8][8];
#pragma unroll
    for (int i = 0; i < 8; ++i)
#pragma unroll
        for (int j = 0; j < 8; ++j) acc[i][j] = 0.f;
    for (int kc = 0; kc < 128; kc += 16) {
        float wt = wtime[kc + kk], bt = btime[kc + kk];
        float cv[8];
#pragma unroll
        for (int i = 0; i < 8; ++i) cv[i] = cosf(tv[i] * wt + bt);
#pragma unroll
        for (int i = 0; i < 8; ++i) sC[wave][kk][e0 + i] = cv[i];
        asm volatile("" ::: "memory");
#pragma unroll
        for (int r = 0; r < 16; ++r) {
            f32x4 a0 = *(const f32x4*)&sC[wave][r][eg * 8];
            f32x4 a1 = *(const f32x4*)&sC[wave][r][eg * 8 + 4];
            f32x4 b0 = *(const f32x4*)&wc[(size_t)(kc + r) * 128 + tx * 4];
            f32x4 b1 = *(const f32x4*)&wc[(size_t)(kc + r) * 128 + 64 + tx * 4];
#pragma unroll
            for (int i = 0; i < 8; ++i) {
                float ae = i < 4 ? a0[i] : a1[i - 4];
#pragma unroll
                for (int j = 0; j < 4; ++j) {
                    acc[i][j]     = fmaf(ae, b0[j], acc[i][j]);
                    acc[i][j + 4] = fmaf(ae, b1[j], acc[i][j + 4]);
                }
            }
        }
        asm volatile("" ::: "memory");
    }
    // epilogue: lane covers f = tx*4+j (and 64+tx*4+j), edges eg*8+i
    f32x4 bb0 = *(const f32x4*)&bs1[tx * 4];
    f32x4 bb1 = *(const f32x4*)&bs1[64 + tx * 4];
    f32x4 w20 = *(const f32x4*)&ws2[tx * 4];
    f32x4 w21 = *(const f32x4*)&ws2[64 + tx * 4];
    float myv = 0.f;
#pragma unroll
    for (int i = 0; i < 8; ++i) {
        int r = eg * 8 + i;
        int s = sS[wave][r], d = sD[wave][r];
        const float* As = Ah + (size_t)s * 128;
        const float* Bd = Bh + (size_t)d * 128;
        f32x4 A0 = *(const f32x4*)&As[tx * 4];
        f32x4 A1 = *(const f32x4*)&As[64 + tx * 4];
        f32x4 B0 = *(const f32x4*)&Bd[tx * 4];
        f32x4 B1 = *(const f32x4*)&Bd[64 + tx * 4];
        float v[4];
#pragma unroll
        for (int j = 0; j < 4; ++j) {
            float p0 = acc[i][j] + ((A0[j] + B0[j]) + bb0[j]);
            float p1 = acc[i][j + 4] + ((A1[j] + B1[j]) + bb1[j]);
            v[j] = fmaxf(p0, 0.f) * w20[j] + fmaxf(p1, 0.f) * w21[j];
        }
#pragma unroll
        for (int j = 0; j < 4; ++j) {
            v[j] += __shfl_xor(v[j], 8, 64);
            v[j] += __shfl_xor(v[j], 4, 64);
            v[j] += __shfl_xor(v[j], 2, 64);
            v[j] += __shfl_xor(v[j], 1, 64);
        }
        float vv = (v[0] + v[2]) + (v[1] + v[3]);
        if (tx == i) myv = vv;
    }
    if (tx < 8) {
        int r = eg * 8 + tx;
        unsigned slot = lo + ebase + (unsigned)r;
        if (slot < hi) {
            float b2 = bs2[0];
            float zv = 1.f / (1.f + expf(-(myv + b2)));
            z[sE[wave][r]] = zv;
            atomicAdd(hist1 + (__float_as_uint(zv) >> 16), 1u);
        }
    }
}

__global__ __launch_bounds__(1024) void scank(const unsigned* __restrict__ hist,
                                              unsigned* meta, int kIdx, int outIdx)
{
    __shared__ unsigned s[1024];
    int t = threadIdx.x;
    unsigned K = meta[kIdx];
    unsigned sum = 0;
    for (int i = 0; i < 64; ++i) sum += hist[t * 64 + i];
    s[t] = sum;
    __syncthreads();
    for (int off = 1; off < 1024; off <<= 1) {
        unsigned add = (t + off < 1024) ? s[t + off] : 0u;
        __syncthreads();
        s[t] += add;
        __syncthreads();
    }
    unsigned mine = s[t];
    unsigned after = (t < 1023) ? s[t + 1] : 0u;
    if (mine >= K && after < K) {
        unsigned cum = after;
        for (int b = 63; b >= 0; --b) {
            unsigned c = hist[t * 64 + b];
            cum += c;
            if (cum >= K) {
                meta[outIdx] = (unsigned)(t * 64 + b);
                meta[outIdx + 1] = cum - c;
                meta[outIdx + 2] = K - (cum - c);
                break;
            }
        }
    }
}

__global__ void pass2(const float* __restrict__ z, const unsigned* __restrict__ meta,
                      unsigned* hist2, int E)
{
    int e = blockIdx.x * blockDim.x + threadIdx.x;
    if (e >= E) return;
    unsigned u = __float_as_uint(z[e]);
    if ((u >> 16) == meta[2]) atomicAdd(hist2 + (u & 0xffffu), 1u);
}

__global__ void pass3(const float* __restrict__ z, unsigned* meta,
                      unsigned char* keep, unsigned* eql, int E)
{
    int e = blockIdx.x * blockDim.x + threadIdx.x;
    if (e >= E) return;
    unsigned u = __float_as_uint(z[e]);
    unsigned T = (meta[2] << 16) | (meta[5] & 0xffffu);
    keep[e] = (u > T) ? 1 : 0;
    if (u == T) {
        unsigned slot = atomicAdd(meta + 8, 1u);
        if (slot < 4096u) eql[slot] = (unsigned)e;
    }
}

__global__ void eqres(const unsigned* __restrict__ meta, const unsigned* __restrict__ eql,
                      unsigned char* keep)
{
    __shared__ unsigned list[4096];
    unsigned c = meta[8]; if (c > 4096u) c = 4096u;
    unsigned need = meta[7];
    for (unsigned i = threadIdx.x; i < c; i += blockDim.x) list[i] = eql[i];
    __syncthreads();
    for (unsigned i = threadIdx.x; i < c; i += blockDim.x) {
        unsigned rank = 0;
        for (unsigned j = 0; j < c; ++j) rank += (list[j] < list[i]) ? 1u : 0u;
        if (rank < need) keep[list[i]] = 1;
    }
}

__global__ void degsc(const int* __restrict__ ei, const float* __restrict__ z,
                      const unsigned char* __restrict__ keep, float* deg, int E, int N)
{
    int e = blockIdx.x * blockDim.x + threadIdx.x;
    if (e >= E) return;
    if (keep[e]) atomicAdd(deg + clampi(ei[E + e], N), z[e]);
}

__global__ void dinv_k(float* deg, float* selfn, int N)
{
    int i = blockIdx.x * blockDim.x + threadIdx.x;
    if (i >= N) return;
    float d = deg[i];
    float di = 1.0f / sqrtf(d);   // deg >= 1 (self-loop weight 1)
    deg[i] = di;
    selfn[i] = di * di;
}

__global__ void normcnt(const int* __restrict__ ei, const float* __restrict__ z,
                        const unsigned char* __restrict__ keep, const float* __restrict__ dinv,
                        float* normv, unsigned* cnt, int E, int N)
{
    int e = blockIdx.x * blockDim.x + threadIdx.x;
    if (e >= E) return;
    if (keep[e]) {
        int s = clampi(ei[e], N), d = clampi(ei[E + e], N);
        normv[e] = dinv[s] * z[e] * dinv[d];
        atomicAdd(cnt + d, 1u);
    } else {
        normv[e] = 0.f;
    }
}

__global__ __launch_bounds__(1024) void scan_n(unsigned* cnt, unsigned* fill, int N)
{
    __shared__ unsigned s[1024];
    int t = threadIdx.x;
    int per = (N + 1023) >> 10;
    int lo = t * per; if (lo > N) lo = N;
    int hi = lo + per; if (hi > N) hi = N;
    unsigned sum = 0;
    for (int i = lo; i < hi; ++i) sum += cnt[i];
    s[t] = sum;
    __syncthreads();
    for (int off = 1; off < 1024; off <<= 1) {
        unsigned add = (t >= off) ? s[t - off] : 0u;
        __syncthreads();
        s[t] += add;
        __syncthreads();
    }
    unsigned run = (t > 0) ? s[t - 1] : 0u;
    for (int i = lo; i < hi; ++i) {
        unsigned c = cnt[i];
        cnt[i] = run; fill[i] = run;
        run += c;
    }
    if (t == 1023) cnt[N] = run;
}

__global__ void fillk(const int* __restrict__ ei, const unsigned char* __restrict__ keep,
                      unsigned* fill, unsigned* csr, int E, int N)
{
    int e = blockIdx.x * blockDim.x + threadIdx.x;
    if (e >= E) return;
    if (keep[e]) {
        unsigned p = atomicAdd(fill + clampi(ei[E + e], N), 1u);
        csr[p] = (unsigned)e;
    }
}

// GCN aggregation: hout[n] = (relu?)( bias + selfn[n]*m[n] + sum_e norm[e]*m[src[e]] )
__global__ __launch_bounds__(256) void agg_k(const bf16_t* __restrict__ m,
        const int* __restrict__ ei, const float* __restrict__ normv,
        const unsigned* __restrict__ ofs, const unsigned* __restrict__ csr,
        const float* __restrict__ selfn, const float* __restrict__ bias,
        float* __restrict__ hout, bf16_t* __restrict__ houtb, int N, int E, int dorelu)
{
    int wave = threadIdx.x >> 6, lane = threadIdx.x & 63;
    int n = blockIdx.x * 4 + wave;
    if (n >= N) return;
    int f = 2 * lane;
    float sn = selfn[n];
    bf16x2 mv = *(const bf16x2*)(m + (size_t)n * 128 + f);
    float a0 = bias[f] + sn * (float)mv[0];
    float a1 = bias[f + 1] + sn * (float)mv[1];
    unsigned lo = ofs[n], hi = ofs[n + 1];
    unsigned deg = hi - lo;
    unsigned cap = deg < 64u ? deg : 64u;
    int s_l = 0; float w_l = 0.f;
    if (lane < (int)cap) {
        unsigned e = csr[lo + lane];
        s_l = clampi(ei[e], N);
        w_l = normv[e];
    }
    for (unsigned j = 0; j < cap; ++j) {
        int s = __shfl(s_l, (int)j, 64);
        float w = __shfl(w_l, (int)j, 64);
        bf16x2 v = *(const bf16x2*)(m + (size_t)s * 128 + f);
        a0 = fmaf(w, (float)v[0], a0);
        a1 = fmaf(w, (float)v[1], a1);
    }
    for (unsigned idx = lo + 64; idx < hi; ++idx) {
        unsigned e = csr[idx];
        int s = clampi(ei[e], N);
        float w = normv[e];
        bf16x2 v = *(const bf16x2*)(m + (size_t)s * 128 + f);
        a0 = fmaf(w, (float)v[0], a0);
        a1 = fmaf(w, (float)v[1], a1);
    }
    if (dorelu) { a0 = fmaxf(a0, 0.f); a1 = fmaxf(a1, 0.f); }
    f32x2 o; o[0] = a0; o[1] = a1;
    *(f32x2*)(hout + (size_t)n * 128 + f) = o;
    if (houtb) {
        bf16x2 ob; ob[0] = (bf16_t)a0; ob[1] = (bf16_t)a1;
        *(bf16x2*)(houtb + (size_t)n * 128 + f) = ob;
    }
}

__global__ __launch_bounds__(256) void decode_k(const int* __restrict__ eli,
        const float* __restrict__ hnew, const float* __restrict__ wdec,
        const float* __restrict__ bdec, float* __restrict__ pred, int L, int N)
{
    int wave = threadIdx.x >> 6, lane = threadIdx.x & 63;
    int l = blockIdx.x * 4 + wave;
    if (l >= L) return;
    int a = clampi(eli[l], N), b = clampi(eli[L + l], N);
    f32x2 ha = *(const f32x2*)(hnew + (size_t)a * 128 + 2 * lane);
    f32x2 hb = *(const f32x2*)(hnew + (size_t)b * 128 + 2 * lane);
    f32x2 w  = *(const f32x2*)(wdec + 2 * lane);
    float acc = ha[0] * hb[0] * w[0] + ha[1] * hb[1] * w[1];
    for (int off = 32; off; off >>= 1) acc += __shfl_down(acc, off, 64);
    if (lane == 0) pred[l] = acc + bdec[0];
}

// ---------------------------------------------------------------------------
extern "C" void kernel_launch(void* const* d_in, const int* in_sizes, int n_in,
                              void* d_out, int out_size, void* d_ws, size_t ws_size,
                              hipStream_t stream)
{
    (void)n_in; (void)out_size;
    const float* x      = (const float*)d_in[0];
    const int*   ei     = (const int*)d_in[1];
    const int*   eli    = (const int*)d_in[2];
    const float* etime  = (const float*)d_in[3];
    const float* prev   = (const float*)d_in[4];
    const float* w_mlp  = (const float*)d_in[5];
    const float* b_mlp  = (const float*)d_in[6];
    const float* w_time = (const float*)d_in[7];
    const float* b_time = (const float*)d_in[8];
    const float* w_s1   = (const float*)d_in[9];
    const float* b_s1   = (const float*)d_in[10];
    const float* w_s2   = (const float*)d_in[11];
    const float* b_s2   = (const float*)d_in[12];
    const float* gcn_w  = (const float*)d_in[13];
    const float* gcn_b  = (const float*)d_in[14];
    const float* gru_wi = (const float*)d_in[15];
    const float* gru_wh = (const float*)d_in[16];
    const float* gru_bi = (const float*)d_in[17];
    const float* gru_bh = (const float*)d_in[18];
    const float* w_dec  = (const float*)d_in[19];
    const float* b_dec  = (const float*)d_in[20];

    const int E  = in_sizes[3];
    const int N  = in_sizes[0] / 128;
    const int L  = in_sizes[2] / 2;
    const int K  = (int)(0.8 * (double)E);
    const int Nh = (N + 1) / 2;

    char* wsp = (char*)d_ws;
    size_t off = 0;
    auto alloc = [&](size_t bytes) -> void* {
        void* p = wsp + off;
        off += (bytes + 255) & ~(size_t)255;
        return p;
    };
    unsigned* meta  = (unsigned*)alloc(64 * 4);
    unsigned* bmeta = (unsigned*)alloc(64 * 4);
    unsigned* elist = (unsigned*)alloc((size_t)E * 4);
    unsigned* eql   = (unsigned*)alloc(4096 * 4);
    unsigned* hist1 = (unsigned*)alloc(65536 * 4);
    unsigned* hist2 = (unsigned*)alloc(65536 * 4);
    unsigned* cnt   = (unsigned*)alloc((size_t)(N + 1) * 4);
    unsigned* fill  = (unsigned*)alloc((size_t)N * 4);
    float* deg      = (float*)alloc((size_t)N * 4);
    float* selfn    = (float*)alloc((size_t)N * 4);
    float* zbuf     = (float*)alloc((size_t)E * 4);
    unsigned char* keep = (unsigned char*)alloc((size_t)E);
    float* normv    = (float*)alloc((size_t)E * 4);
    unsigned* csr   = (unsigned*)alloc((size_t)E * 4);
    // bf16 transposed weights for MFMA
    bf16_t* wmlpT = (bf16_t*)alloc(128 * 128 * 2);
    bf16_t* g0T   = (bf16_t*)alloc(128 * 128 * 2);
    bf16_t* g1T   = (bf16_t*)alloc(128 * 128 * 2);
    bf16_t* wiT   = (bf16_t*)alloc(384 * 128 * 2);
    bf16_t* whT   = (bf16_t*)alloc(384 * 128 * 2);

    // Projection buffers: full [N,128] fp32 A and B if workspace allows
    // (single z pass, no bucketing); else half-size slots with 4 bucket phases.
    size_t fullBytes = (size_t)N * 128 * 4;
    size_t halfBytes = (size_t)Nh * 128 * 4;
    bool full = (off + 2 * ((fullBytes + 255) & ~(size_t)255)) <= ws_size;
    char* slot0; char* slot1;
    float* Ahalf; float* Bhalf;
    if (full) {
        slot0 = (char*)alloc(fullBytes);
        slot1 = (char*)alloc(fullBytes);
        Ahalf = (float*)slot0;            // full A
        Bhalf = (float*)slot1;            // full B
    } else {
        slot0 = (char*)alloc(halfBytes);
        slot1 = (char*)alloc(halfBytes);
        Ahalf = (float*)slot0;
        Bhalf = (float*)slot1;
    }
    bf16_t* xbf   = (bf16_t*)slot0;      // bf16 copy of x / h
    bf16_t* mbuf  = (bf16_t*)slot1;

    // fp32 outputs: pred [L], h_new [N,128]. h_new region doubles as hb (fp32 h).
    float* out_pred = (float*)d_out;
    float* hnew     = (float*)d_out + L;
    float* hb       = hnew;

    // ---- init (fused) ----
    initall<<<1024, 256, 0, stream>>>(meta, bmeta, hist1, hist2, cnt, deg, N, K);

    // ---- bf16 transposed weights for MFMA ----
    transp_k<<<64, 256, 0, stream>>>(w_mlp, wmlpT, 128, 128, 0);
    transp_k<<<64, 256, 0, stream>>>(gcn_w, g0T, 128, 128, 0);
    transp_k<<<64, 256, 0, stream>>>(gcn_w, g1T, 128, 128, 128);
    transp_k<<<192, 256, 0, stream>>>(gru_wi, wiT, 384, 384, 0);
    transp_k<<<192, 256, 0, stream>>>(gru_wh, whT, 384, 384, 0);

    tmin_k<<<512, 256, 0, stream>>>(etime, meta, E);

    // ---- z pass ----
    const int zgrid = (E + 127) / 128;
    const float* wc = w_s1 + 256 * 128;
    if (full) {
        proj2w<<<(N + 127) / 128, 256, 0, stream>>>(prev, w_s1, Ahalf, N, 0);
        proj2w<<<(N + 127) / 128, 256, 0, stream>>>(prev, w_s1 + 128 * 128, Bhalf, N, 0);
        zgemmw<<<zgrid, 256, 0, stream>>>(etime, ei, (const unsigned*)nullptr, bmeta, -1,
                0, 0, Ahalf, Bhalf, w_time, b_time, wc, b_s1, w_s2, b_s2,
                meta, zbuf, hist1, E, N);
    } else {
        // bucket edges by (s>=Nh, d>=Nh)
        bcount_k<<<(E + 255) / 256, 256, 0, stream>>>(ei, bmeta, E, Nh, N);
        bscan_k<<<1, 64, 0, stream>>>(bmeta);
        bfill_k<<<(E + 255) / 256, 256, 0, stream>>>(ei, bmeta, elist, E, Nh, N);
        const int NA0 = Nh, NA1 = N - Nh;
        auto zlaunch = [&](int b, int so, int doo) {
            zgemmw<<<zgrid, 256, 0, stream>>>(etime, ei, elist, bmeta, b, so, doo,
                    Ahalf, Bhalf, w_time, b_time, wc, b_s1, w_s2, b_s2,
                    meta, zbuf, hist1, E, N);
        };
        proj2w<<<(NA0 + 127) / 128, 256, 0, stream>>>(prev, w_s1, Ahalf, NA0, 0);
        proj2w<<<(NA0 + 127) / 128, 256, 0, stream>>>(prev, w_s1 + 128 * 128, Bhalf, NA0, 0);
        zlaunch(0, 0, 0);
        proj2w<<<(NA1 + 127) / 128, 256, 0, stream>>>(prev, w_s1 + 128 * 128, Bhalf, NA1, Nh);
        zlaunch(1, 0, Nh);
        proj2w<<<(NA1 + 127) / 128, 256, 0, stream>>>(prev, w_s1, Ahalf, NA1, Nh);
        zlaunch(3, Nh, Nh);
        proj2w<<<(NA0 + 127) / 128, 256, 0, stream>>>(prev, w_s1 + 128 * 128, Bhalf, NA0, 0);
        zlaunch(2, Nh, 0);
    }

    // ---- exact top-k radix select ----
    scank<<<1, 1024, 0, stream>>>(hist1, meta, 1, 2);
    pass2<<<(E + 255) / 256, 256, 0, stream>>>(zbuf, meta, hist2, E);
    scank<<<1, 1024, 0, stream>>>(hist2, meta, 4, 5);
    pass3<<<(E + 255) / 256, 256, 0, stream>>>(zbuf, meta, keep, eql, E);
    eqres<<<1, 256, 0, stream>>>(meta, eql, keep);

    // ---- degrees / norms / CSR ----
    degsc<<<(E + 255) / 256, 256, 0, stream>>>(ei, zbuf, keep, deg, E, N);
    dinv_k<<<(N + 255) / 256, 256, 0, stream>>>(deg, selfn, N);
    normcnt<<<(E + 255) / 256, 256, 0, stream>>>(ei, zbuf, keep, deg, normv, cnt, E, N);
    scan_n<<<1, 1024, 0, stream>>>(cnt, fill, N);
    fillk<<<(E + 255) / 256, 256, 0, stream>>>(ei, keep, fill, csr, E, N);

    // ---- h0 = relu(x @ w_mlp + b_mlp): fp32 in d_out, bf16 fused (in-place) ----
    cvtb_k<<<2048, 256, 0, stream>>>(x, 0, xbf, N * 128);
    gemm128<128><<<(N + 63) / 64, 256, 0, stream>>>(xbf, wmlpT, b_mlp, hb, xbf, N, 1);

    // ---- GCN layers (h fp32 in d_out; bf16 copies fused into epilogues) ----
    gemm128<128><<<(N + 63) / 64, 256, 0, stream>>>(xbf, g0T, nullptr, nullptr, mbuf, N, 0);
    agg_k<<<(N + 3) / 4, 256, 0, stream>>>(mbuf, ei, normv, cnt, csr, selfn, gcn_b, hb, xbf, N, E, 1);
    gemm128<128><<<(N + 63) / 64, 256, 0, stream>>>(xbf, g1T, nullptr, nullptr, mbuf, N, 0);
    agg_k<<<(N + 3) / 4, 256, 0, stream>>>(mbuf, ei, normv, cnt, csr, selfn, gcn_b + 128, hb, xbf, N, E, 0);

    // ---- fused GRU: h_new = gate(xbf@wiT+bi, prev@whT+bh, prev) ----
    gru_k<<<(N + 63) / 64, 256, 0, stream>>>(xbf, prev, wiT, whT, gru_bi, gru_bh, hnew, N);

    // ---- link decoder (fp32) ----
    decode_k<<<(L + 3) / 4, 256, 0, stream>>>(eli, hnew, w_dec, b_dec, out_pred, L, N);
}